// Round 1
// baseline (5902.020 us; speedup 1.0000x reference)
//
#include <hip/hip_runtime.h>
#include <hip/hip_bf16.h>
#include <math.h>

#define M_ROWS 5792   // B*N
#define NTOK 181
#define DMODEL 512
#define NH 8
#define HD 64
#define DFFN 2048
#define NLAYER 6

__device__ __forceinline__ float gelu_f(float v) {
    return 0.5f * v * (1.0f + erff(v * 0.70710678118654752f));
}

// ---------------- x = x0 + pos_embed ----------------
__global__ void add_pos_kernel(const float* __restrict__ x0, const float* __restrict__ pos,
                               float* __restrict__ x) {
    int idx = blockIdx.x * 256 + threadIdx.x;          // float4 index
    const int total = M_ROWS * (DMODEL / 4);
    if (idx >= total) return;
    int col = idx & 127;                                // 128 float4 per row
    int m   = idx >> 7;
    int t   = m % NTOK;
    float4 a = ((const float4*)x0)[idx];
    float4 p = ((const float4*)pos)[t * 128 + col];
    a.x += p.x; a.y += p.y; a.z += p.z; a.w += p.w;
    ((float4*)x)[idx] = a;
}

// ---------------- tiled fp32 GEMM: C = A(MxK) @ W(KxN) + bias, optional GELU ----
// 64x64 tile, BK=16, 256 threads, 4x4 per thread.
template<int EPI>   // 0 = none, 1 = gelu
__global__ __launch_bounds__(256) void gemm_kernel(const float* __restrict__ A,
                                                   const float* __restrict__ W,
                                                   const float* __restrict__ bias,
                                                   float* __restrict__ C,
                                                   int M, int K, int N) {
    __shared__ float As[16][68];   // [k][m], padded
    __shared__ float Bs[16][68];   // [k][n], padded
    const int tid = threadIdx.x;
    const int tx = tid & 15, ty = tid >> 4;
    const int arow = tid >> 2, acol = (tid & 3) << 2;
    const int brow = tid >> 4, bcol = (tid & 15) << 2;
    const int row0 = blockIdx.x * 64, col0 = blockIdx.y * 64;

    const bool aval = (row0 + arow) < M;
    const float* Aptr = A + (size_t)(row0 + arow) * K + acol;
    const float* Wptr = W + (size_t)brow * N + col0 + bcol;

    float acc[4][4] = {{0.f,0.f,0.f,0.f},{0.f,0.f,0.f,0.f},{0.f,0.f,0.f,0.f},{0.f,0.f,0.f,0.f}};

    for (int k0 = 0; k0 < K; k0 += 16) {
        float4 av = make_float4(0.f, 0.f, 0.f, 0.f);
        if (aval) av = *(const float4*)(Aptr + k0);
        float4 bv = *(const float4*)(Wptr + (size_t)k0 * N);
        As[acol + 0][arow] = av.x;
        As[acol + 1][arow] = av.y;
        As[acol + 2][arow] = av.z;
        As[acol + 3][arow] = av.w;
        *(float4*)(&Bs[brow][bcol]) = bv;
        __syncthreads();
        #pragma unroll
        for (int kk = 0; kk < 16; ++kk) {
            float4 a = *(const float4*)(&As[kk][ty << 2]);
            float4 b = *(const float4*)(&Bs[kk][tx << 2]);
            acc[0][0] += a.x*b.x; acc[0][1] += a.x*b.y; acc[0][2] += a.x*b.z; acc[0][3] += a.x*b.w;
            acc[1][0] += a.y*b.x; acc[1][1] += a.y*b.y; acc[1][2] += a.y*b.z; acc[1][3] += a.y*b.w;
            acc[2][0] += a.z*b.x; acc[2][1] += a.z*b.y; acc[2][2] += a.z*b.z; acc[2][3] += a.z*b.w;
            acc[3][0] += a.w*b.x; acc[3][1] += a.w*b.y; acc[3][2] += a.w*b.z; acc[3][3] += a.w*b.w;
        }
        __syncthreads();
    }

    const float4 bb = *(const float4*)(bias + col0 + (tx << 2));
    #pragma unroll
    for (int i = 0; i < 4; ++i) {
        int r = row0 + (ty << 2) + i;
        if (r < M) {
            float4 o;
            o.x = acc[i][0] + bb.x;
            o.y = acc[i][1] + bb.y;
            o.z = acc[i][2] + bb.z;
            o.w = acc[i][3] + bb.w;
            if (EPI == 1) { o.x = gelu_f(o.x); o.y = gelu_f(o.y); o.z = gelu_f(o.z); o.w = gelu_f(o.w); }
            *(float4*)(C + (size_t)r * N + col0 + (tx << 2)) = o;
        }
    }
}

// ---------------- relative-position bias r[j] = dot(rel_pos[j], rpe_w) --------
__global__ void rbias_kernel(const float* __restrict__ rel_pos, const float* __restrict__ rpe_w,
                             float* __restrict__ r) {
    int j = blockIdx.x * 64 + threadIdx.x;
    if (j >= 2 * NTOK - 1) return;
    const float* rp = rel_pos + (size_t)j * HD;
    float s = 0.f;
    #pragma unroll
    for (int d = 0; d < HD; d += 4) {
        float4 a = *(const float4*)(rp + d);
        float4 b = *(const float4*)(rpe_w + d);
        s += a.x*b.x + a.y*b.y + a.z*b.z + a.w*b.w;
    }
    r[j] = s;
}

// ---------------- fused attention: per (b,h) block ---------------------------
// K staged in LDS (XOR-swizzled), Q broadcast from global, V streamed from L2.
__global__ __launch_bounds__(256) void attn_kernel(const float* __restrict__ qkv,
                                                   const float* __restrict__ rb,
                                                   float* __restrict__ outb) {
    __shared__ float Ks[192 * 64];      // rows padded to 192 for safe OOB reads
    __shared__ float wsm[4][192];
    __shared__ float rs[384];
    const int b  = blockIdx.x >> 3;
    const int hh = blockIdx.x & 7;
    const int tid = threadIdx.x, lane = tid & 63, wv = tid >> 6;
    const float* base = qkv + (size_t)b * NTOK * 1536 + hh * 64;

    for (int i = tid; i < NTOK * 16; i += 256) {
        int t = i >> 4, f4 = i & 15;
        float4 v = *(const float4*)(base + (size_t)t * 1536 + 512 + (f4 << 2));
        *(float4*)(&Ks[t * 64 + ((f4 ^ (t & 15)) << 2)]) = v;
    }
    for (int i = tid; i < 2 * NTOK - 1; i += 256) rs[i] = rb[i];
    __syncthreads();

    const float scale = 0.125f;
    const int kg = lane >> 4, f4i = lane & 15;
    const int k0 = lane, k1 = lane + 64, k2 = lane + 128;

    for (int qi = 0; qi < 46; ++qi) {
        const int q = qi * 4 + wv;
        const bool act = q < NTOK;
        if (act) {
            const float* qrow = base + (size_t)q * 1536;
            float s0 = 0.f, s1 = 0.f, s2 = 0.f;
            #pragma unroll 4
            for (int f4 = 0; f4 < 16; ++f4) {
                float4 qv = *(const float4*)(qrow + (f4 << 2));
                float4 ka = *(const float4*)(&Ks[k0 * 64 + ((f4 ^ (k0 & 15)) << 2)]);
                float4 kb = *(const float4*)(&Ks[k1 * 64 + ((f4 ^ (k1 & 15)) << 2)]);
                float4 kc = *(const float4*)(&Ks[k2 * 64 + ((f4 ^ (k2 & 15)) << 2)]);
                s0 += qv.x*ka.x + qv.y*ka.y + qv.z*ka.z + qv.w*ka.w;
                s1 += qv.x*kb.x + qv.y*kb.y + qv.z*kb.z + qv.w*kb.w;
                s2 += qv.x*kc.x + qv.y*kc.y + qv.z*kc.z + qv.w*kc.w;
            }
            s0 = s0 * scale + rs[k0 - q + 180];
            s1 = s1 * scale + rs[k1 - q + 180];
            s2 = (k2 < NTOK) ? (s2 * scale + rs[k2 - q + 180]) : -1e30f;
            float mx = fmaxf(s0, fmaxf(s1, s2));
            #pragma unroll
            for (int off = 32; off; off >>= 1) mx = fmaxf(mx, __shfl_xor(mx, off));
            float e0 = expf(s0 - mx), e1 = expf(s1 - mx), e2 = expf(s2 - mx);
            float sm = e0 + e1 + e2;
            #pragma unroll
            for (int off = 32; off; off >>= 1) sm += __shfl_xor(sm, off);
            float inv = 1.0f / sm;
            wsm[wv][k0] = e0 * inv;
            wsm[wv][k1] = e1 * inv;
            wsm[wv][k2] = e2 * inv;
        }
        __syncthreads();
        if (act) {
            float4 acc = make_float4(0.f, 0.f, 0.f, 0.f);
            const float* vbase = base + 1024 + (f4i << 2);
            for (int k = kg; k < NTOK; k += 4) {
                float wgt = wsm[wv][k];
                float4 v = *(const float4*)(vbase + (size_t)k * 1536);
                acc.x += wgt * v.x; acc.y += wgt * v.y; acc.z += wgt * v.z; acc.w += wgt * v.w;
            }
            #pragma unroll
            for (int off = 16; off < 64; off <<= 1) {
                acc.x += __shfl_xor(acc.x, off);
                acc.y += __shfl_xor(acc.y, off);
                acc.z += __shfl_xor(acc.z, off);
                acc.w += __shfl_xor(acc.w, off);
            }
            if (lane < 16)
                *(float4*)(outb + (size_t)(b * NTOK + q) * 512 + hh * 64 + (lane << 2)) = acc;
        }
        __syncthreads();
    }
}

// ---------------- x = LayerNorm(x + y) * g + b ; one wave per row ------------
__global__ __launch_bounds__(256) void lnres_kernel(float* __restrict__ x, const float* __restrict__ y,
                                                    const float* __restrict__ g, const float* __restrict__ bb) {
    const int row = blockIdx.x * 4 + (threadIdx.x >> 6);
    const int l = threadIdx.x & 63;
    float* xr = x + (size_t)row * 512;
    const float* yr = y + (size_t)row * 512;
    float4 v0 = *(const float4*)(xr + (l << 2));
    float4 v1 = *(const float4*)(xr + 256 + (l << 2));
    const float4 u0 = *(const float4*)(yr + (l << 2));
    const float4 u1 = *(const float4*)(yr + 256 + (l << 2));
    v0.x += u0.x; v0.y += u0.y; v0.z += u0.z; v0.w += u0.w;
    v1.x += u1.x; v1.y += u1.y; v1.z += u1.z; v1.w += u1.w;
    float s = v0.x + v0.y + v0.z + v0.w + v1.x + v1.y + v1.z + v1.w;
    #pragma unroll
    for (int off = 32; off; off >>= 1) s += __shfl_xor(s, off);
    const float m = s * (1.0f / 512.0f);
    float d0 = v0.x - m, d1 = v0.y - m, d2 = v0.z - m, d3 = v0.w - m;
    float d4 = v1.x - m, d5 = v1.y - m, d6 = v1.z - m, d7 = v1.w - m;
    float q = d0*d0 + d1*d1 + d2*d2 + d3*d3 + d4*d4 + d5*d5 + d6*d6 + d7*d7;
    #pragma unroll
    for (int off = 32; off; off >>= 1) q += __shfl_xor(q, off);
    const float r = rsqrtf(q * (1.0f / 512.0f) + 1e-5f);
    const float4 g0 = *(const float4*)(g + (l << 2));
    const float4 g1 = *(const float4*)(g + 256 + (l << 2));
    const float4 b0 = *(const float4*)(bb + (l << 2));
    const float4 b1 = *(const float4*)(bb + 256 + (l << 2));
    float4 o0, o1;
    o0.x = d0 * r * g0.x + b0.x; o0.y = d1 * r * g0.y + b0.y;
    o0.z = d2 * r * g0.z + b0.z; o0.w = d3 * r * g0.w + b0.w;
    o1.x = d4 * r * g1.x + b1.x; o1.y = d5 * r * g1.y + b1.y;
    o1.z = d6 * r * g1.z + b1.z; o1.w = d7 * r * g1.w + b1.w;
    *(float4*)(xr + (l << 2)) = o0;
    *(float4*)(xr + 256 + (l << 2)) = o1;
}

// ---------------- head MLP: shift = relu(x@w1+b1)@w2+b2 ; wave per row -------
__global__ __launch_bounds__(256) void head_kernel(const float* __restrict__ x, const float* __restrict__ w1,
                                                   const float* __restrict__ b1, const float* __restrict__ w2,
                                                   const float* __restrict__ b2, float* __restrict__ shift) {
    const int row = blockIdx.x * 4 + (threadIdx.x >> 6);
    const int j = threadIdx.x & 63;
    const float* xr = x + (size_t)row * 512;
    float acc = 0.f;
    #pragma unroll 4
    for (int d = 0; d < 512; d += 4) {
        const float4 xv = *(const float4*)(xr + d);
        acc += xv.x * w1[(d + 0) * 64 + j];
        acc += xv.y * w1[(d + 1) * 64 + j];
        acc += xv.z * w1[(d + 2) * 64 + j];
        acc += xv.w * w1[(d + 3) * 64 + j];
    }
    float h = fmaxf(acc + b1[j], 0.f) * w2[j];
    #pragma unroll
    for (int off = 32; off; off >>= 1) h += __shfl_xor(h, off);
    if (j == 0) shift[row] = h + b2[0];
}

// ---------------- bilinear warp ----------------------------------------------
__global__ void warp_kernel(const float* __restrict__ x0, const float* __restrict__ shift,
                            const int* __restrict__ pms, float* __restrict__ warped) {
    int idx = blockIdx.x * 256 + threadIdx.x;
    if (idx >= M_ROWS * DMODEL) return;
    int c = idx & 511;
    int m = idx >> 9;
    int t = m % NTOK;
    int b = m / NTOK;
    float max_shift = (float)pms[0];
    float sh = shift[m];
    float flow = sh * max_shift / 256.0f;
    float gx = 2.0f * ((float)c / 511.0f - 0.5f) + flow;
    float ix = ((gx + 1.0f) * 512.0f - 1.0f) * 0.5f;
    ix = fminf(fmaxf(ix, 0.0f), 511.0f);
    float gy = 2.0f * ((float)t / 180.0f - 0.5f);
    float iy = ((gy + 1.0f) * 181.0f - 1.0f) * 0.5f;
    iy = fminf(fmaxf(iy, 0.0f), 180.0f);
    float ix0f = floorf(ix), iy0f = floorf(iy);
    float wx = ix - ix0f, wy = iy - iy0f;
    int ix0 = min(max((int)ix0f, 0), 511);
    int ix1 = min(ix0 + 1, 511);
    int iy0 = min(max((int)iy0f, 0), 180);
    int iy1 = min(iy0 + 1, 180);
    const float* xb = x0 + (size_t)b * NTOK * 512;
    float v00 = xb[iy0 * 512 + ix0], v01 = xb[iy0 * 512 + ix1];
    float v10 = xb[iy1 * 512 + ix0], v11 = xb[iy1 * 512 + ix1];
    warped[idx] = (1.f - wy) * ((1.f - wx) * v00 + wx * v01) + wy * ((1.f - wx) * v10 + wx * v11);
}

extern "C" void kernel_launch(void* const* d_in, const int* in_sizes, int n_in,
                              void* d_out, int out_size, void* d_ws, size_t ws_size,
                              hipStream_t stream) {
    const float* x0   = (const float*)d_in[0];
    const int*   pms  = (const int*)d_in[1];
    const float* pos  = (const float*)d_in[2];
    const float* qkvw = (const float*)d_in[3];
    const float* qkvb = (const float*)d_in[4];
    const float* outw = (const float*)d_in[5];
    const float* outbp= (const float*)d_in[6];
    const float* relp = (const float*)d_in[7];
    const float* rpew = (const float*)d_in[8];
    const float* ln1g = (const float*)d_in[9];
    const float* ln1b = (const float*)d_in[10];
    const float* fw1  = (const float*)d_in[11];
    const float* fb1  = (const float*)d_in[12];
    const float* fw2  = (const float*)d_in[13];
    const float* fb2  = (const float*)d_in[14];
    const float* ln2g = (const float*)d_in[15];
    const float* ln2b = (const float*)d_in[16];
    const float* mw1  = (const float*)d_in[17];
    const float* mb1  = (const float*)d_in[18];
    const float* mw2  = (const float*)d_in[19];
    const float* mb2  = (const float*)d_in[20];

    float* out   = (float*)d_out;
    float* x     = (float*)d_ws;                              // 2,965,504
    float* qkv   = x + (size_t)M_ROWS * 512;                  // 8,896,512
    float* attnb = qkv + (size_t)M_ROWS * 1536;               // 2,965,504
    float* ybuf  = attnb + (size_t)M_ROWS * 512;              // 2,965,504
    float* rbias = ybuf + (size_t)M_ROWS * 512;               // 512
    float* hbuf  = qkv;   // FFN hidden aliases qkv+attnb (both dead by then)

    add_pos_kernel<<<(M_ROWS * 128 + 255) / 256, 256, 0, stream>>>(x0, pos, x);

    for (int i = 0; i < NLAYER; ++i) {
        rbias_kernel<<<6, 64, 0, stream>>>(relp + (size_t)i * (2 * NTOK - 1) * HD, rpew + i * HD, rbias);
        gemm_kernel<0><<<dim3(91, 24), 256, 0, stream>>>(x, qkvw + (size_t)i * 512 * 1536,
                                                         qkvb + i * 1536, qkv, M_ROWS, 512, 1536);
        attn_kernel<<<256, 256, 0, stream>>>(qkv, rbias, attnb);
        gemm_kernel<0><<<dim3(91, 8), 256, 0, stream>>>(attnb, outw + (size_t)i * 512 * 512,
                                                        outbp + i * 512, ybuf, M_ROWS, 512, 512);
        lnres_kernel<<<1448, 256, 0, stream>>>(x, ybuf, ln1g + i * 512, ln1b + i * 512);
        gemm_kernel<1><<<dim3(91, 32), 256, 0, stream>>>(x, fw1 + (size_t)i * 512 * 2048,
                                                         fb1 + i * 2048, hbuf, M_ROWS, 512, 2048);
        gemm_kernel<0><<<dim3(91, 8), 256, 0, stream>>>(hbuf, fw2 + (size_t)i * 2048 * 512,
                                                        fb2 + i * 512, ybuf, M_ROWS, 2048, 512);
        lnres_kernel<<<1448, 256, 0, stream>>>(x, ybuf, ln2g + i * 512, ln2b + i * 512);
    }

    head_kernel<<<1448, 256, 0, stream>>>(x, mw1, mb1, mw2, mb2, out);
    warp_kernel<<<(M_ROWS * 512 + 255) / 256, 256, 0, stream>>>(x0, out, pms, out + M_ROWS);
}

// Round 3
// 2588.673 us; speedup vs baseline: 2.2799x; 2.2799x over previous
//
#include <hip/hip_runtime.h>
#include <hip/hip_bf16.h>
#include <math.h>

#define M_ROWS 5792   // B*N
#define NTOK 181
#define NLAYER 6

typedef __attribute__((ext_vector_type(8))) _Float16 f16x8;
typedef __attribute__((ext_vector_type(4))) float f32x4;

__device__ __forceinline__ ushort f2h(float f) {
    union { _Float16 h; ushort u; } v;
    v.h = (_Float16)f;            // v_cvt_f16_f32, round-to-nearest-even
    return v.u;
}
__device__ __forceinline__ float gelu_f(float v) {
    return 0.5f * v * (1.0f + erff(v * 0.70710678118654752f));
}
__device__ __forceinline__ void async16(const void* g, void* l) {
    __builtin_amdgcn_global_load_lds((const __attribute__((address_space(1))) void*)g,
                                     (__attribute__((address_space(3))) void*)l, 16, 0, 0);
}

// ---------------- weight transpose + f16 convert: W[K][N] f32 -> Wt[N][K] f16 ---
__global__ __launch_bounds__(256) void wt_kernel(const float* __restrict__ W,
                                                 ushort* __restrict__ Wt, int K, int N) {
    __shared__ float t[64][65];
    const size_t ls = (size_t)blockIdx.z * K * N;
    const float* Wl = W + ls;
    ushort* Wtl = Wt + ls;
    const int k0 = blockIdx.x * 64, n0 = blockIdx.y * 64;
    const int tr = threadIdx.x >> 6, tc = threadIdx.x & 63;
    #pragma unroll
    for (int i = 0; i < 16; ++i) {
        const int r = i * 4 + tr;
        t[r][tc] = Wl[(size_t)(k0 + r) * N + n0 + tc];
    }
    __syncthreads();
    #pragma unroll
    for (int i = 0; i < 16; ++i) {
        const int r = i * 4 + tr;
        Wtl[(size_t)(n0 + r) * K + k0 + tc] = f2h(t[tc][r]);
    }
}

// ---------------- x = x0 + pos_embed (f32 + f16 shadow) ----------------
__global__ void add_pos_kernel(const float* __restrict__ x0, const float* __restrict__ pos,
                               float* __restrict__ x, ushort* __restrict__ xb) {
    int idx = blockIdx.x * 256 + threadIdx.x;          // float4 index
    const int total = M_ROWS * 128;
    if (idx >= total) return;
    int col = idx & 127;
    int m   = idx >> 7;
    int t   = m % NTOK;
    float4 a = ((const float4*)x0)[idx];
    float4 p = ((const float4*)pos)[t * 128 + col];
    a.x += p.x; a.y += p.y; a.z += p.z; a.w += p.w;
    ((float4*)x)[idx] = a;
    ((ushort4*)xb)[idx] = make_ushort4(f2h(a.x), f2h(a.y), f2h(a.z), f2h(a.w));
}

// ---------------- f16 MFMA GEMM: C = A(MxK,f16) @ Bt(NxK,f16)^T + bias --------
// BM x 128 tile, BK=32, 4 waves (2x2), EPI: 0 = f32 out, 1 = gelu -> f16 out
template<int BM, int EPI>
__global__ __launch_bounds__(256) void mfma_gemm(const ushort* __restrict__ A,
                                                 const ushort* __restrict__ Bt,
                                                 const float* __restrict__ bias,
                                                 void* __restrict__ Cv,
                                                 int M, int K, int N) {
    constexpr int MREP = BM / 32;
    __shared__ __align__(16) ushort sA[2][BM * 32];
    __shared__ __align__(16) ushort sB[2][128 * 32];
    const int tid = threadIdx.x;
    const int lane = tid & 63;
    const int w = tid >> 6;
    const int wr = w >> 1, wc = w & 1;
    const int row0 = blockIdx.x * BM, col0 = blockIdx.y * 128;
    const int wbase = tid & ~63;

    f32x4 acc[MREP][4];
    const f32x4 zero = {0.f, 0.f, 0.f, 0.f};
    #pragma unroll
    for (int m = 0; m < MREP; ++m)
        #pragma unroll
        for (int n = 0; n < 4; ++n) acc[m][n] = zero;

    auto stage = [&](int buf, int kt) {
        const int k0 = kt << 5;
        #pragma unroll
        for (int i = 0; i < BM / 64; ++i) {
            const int s = i * 256 + tid;           // 16B slot
            const int row = s >> 2;
            const int kbl = (s & 3) ^ ((row >> 1) & 3);   // pre-swizzled source
            int gr = row0 + row; if (gr > M - 1) gr = M - 1;
            async16(A + (size_t)gr * K + k0 + (kbl << 3),
                    &sA[buf][(i * 256 + wbase) * 8]);
        }
        #pragma unroll
        for (int i = 0; i < 2; ++i) {
            const int s = i * 256 + tid;
            const int nr = s >> 2;
            const int kbl = (s & 3) ^ ((nr >> 1) & 3);
            async16(Bt + (size_t)(col0 + nr) * K + k0 + (kbl << 3),
                    &sB[buf][(i * 256 + wbase) * 8]);
        }
    };

    stage(0, 0);
    const int NIT = K >> 5;
    const int l15 = lane & 15, kb = lane >> 4;
    for (int it = 0; it < NIT; ++it) {
        __syncthreads();
        if (it + 1 < NIT) stage((it + 1) & 1, it + 1);
        const int buf = it & 1;
        f16x8 af[MREP], bfr[4];
        #pragma unroll
        for (int m = 0; m < MREP; ++m) {
            const int r = wr * (BM / 2) + m * 16 + l15;
            af[m] = *(const f16x8*)&sA[buf][r * 32 + ((kb ^ ((r >> 1) & 3)) << 3)];
        }
        #pragma unroll
        for (int n = 0; n < 4; ++n) {
            const int r = wc * 64 + n * 16 + l15;
            bfr[n] = *(const f16x8*)&sB[buf][r * 32 + ((kb ^ ((r >> 1) & 3)) << 3)];
        }
        #pragma unroll
        for (int m = 0; m < MREP; ++m)
            #pragma unroll
            for (int n = 0; n < 4; ++n)
                acc[m][n] = __builtin_amdgcn_mfma_f32_16x16x32_f16(af[m], bfr[n], acc[m][n], 0, 0, 0);
    }

    const int crow = row0 + wr * (BM / 2) + (lane >> 4) * 4;
    const int ccol = col0 + wc * 64 + l15;
    #pragma unroll
    for (int m = 0; m < MREP; ++m)
        #pragma unroll
        for (int n = 0; n < 4; ++n) {
            const int gc = ccol + n * 16;
            const float bv = bias[gc];
            #pragma unroll
            for (int r = 0; r < 4; ++r) {
                const int gr = crow + m * 16 + r;
                if (gr < M) {
                    float v = acc[m][n][r] + bv;
                    if (EPI == 1) ((ushort*)Cv)[(size_t)gr * N + gc] = f2h(gelu_f(v));
                    else          ((float*)Cv)[(size_t)gr * N + gc] = v;
                }
            }
        }
}

// ---------------- relative-position bias r[j] = dot(rel_pos[j], rpe_w) --------
__global__ void rbias_kernel(const float* __restrict__ rel_pos, const float* __restrict__ rpe_w,
                             float* __restrict__ r) {
    int j = blockIdx.x * 64 + threadIdx.x;
    if (j >= 2 * NTOK - 1) return;
    const float* rp = rel_pos + (size_t)j * 64;
    float s = 0.f;
    #pragma unroll
    for (int d = 0; d < 64; d += 4) {
        float4 a = *(const float4*)(rp + d);
        float4 b = *(const float4*)(rpe_w + d);
        s += a.x*b.x + a.y*b.y + a.z*b.z + a.w*b.w;
    }
    r[j] = s;
}

// ---------------- fused attention, q-chunked: grid = 256 bh * 8 chunks --------
__global__ __launch_bounds__(256) void attn_kernel(const float* __restrict__ qkv,
                                                   const float* __restrict__ rb,
                                                   ushort* __restrict__ outb) {
    __shared__ float Ks[192 * 64];
    __shared__ float wsm[4][192];
    __shared__ float rs[384];
    const int bh = blockIdx.x >> 3;
    const int qc = blockIdx.x & 7;
    const int b  = bh >> 3;
    const int hh = bh & 7;
    const int tid = threadIdx.x, lane = tid & 63, wv = tid >> 6;
    const float* base = qkv + (size_t)b * NTOK * 1536 + hh * 64;

    for (int i = tid; i < NTOK * 16; i += 256) {
        int t = i >> 4, f4 = i & 15;
        float4 v = *(const float4*)(base + (size_t)t * 1536 + 512 + (f4 << 2));
        *(float4*)(&Ks[t * 64 + ((f4 ^ (t & 15)) << 2)]) = v;
    }
    for (int i = tid; i < 2 * NTOK - 1; i += 256) rs[i] = rb[i];
    __syncthreads();

    const float scale = 0.125f;
    const int kg = lane >> 4, f4i = lane & 15;
    const int k0 = lane, k1 = lane + 64, k2 = lane + 128;

    for (int qi = 0; qi < 6; ++qi) {
        const int q = qc * 24 + qi * 4 + wv;
        const bool act = q < NTOK;
        if (act) {
            const float* qrow = base + (size_t)q * 1536;
            float s0 = 0.f, s1 = 0.f, s2 = 0.f;
            #pragma unroll 4
            for (int f4 = 0; f4 < 16; ++f4) {
                float4 qv = *(const float4*)(qrow + (f4 << 2));
                float4 ka = *(const float4*)(&Ks[k0 * 64 + ((f4 ^ (k0 & 15)) << 2)]);
                float4 kb = *(const float4*)(&Ks[k1 * 64 + ((f4 ^ (k1 & 15)) << 2)]);
                float4 kc = *(const float4*)(&Ks[k2 * 64 + ((f4 ^ (k2 & 15)) << 2)]);
                s0 += qv.x*ka.x + qv.y*ka.y + qv.z*ka.z + qv.w*ka.w;
                s1 += qv.x*kb.x + qv.y*kb.y + qv.z*kb.z + qv.w*kb.w;
                s2 += qv.x*kc.x + qv.y*kc.y + qv.z*kc.z + qv.w*kc.w;
            }
            s0 = s0 * scale + rs[k0 - q + 180];
            s1 = s1 * scale + rs[k1 - q + 180];
            s2 = (k2 < NTOK) ? (s2 * scale + rs[k2 - q + 180]) : -1e30f;
            float mx = fmaxf(s0, fmaxf(s1, s2));
            #pragma unroll
            for (int off = 32; off; off >>= 1) mx = fmaxf(mx, __shfl_xor(mx, off));
            float e0 = expf(s0 - mx), e1 = expf(s1 - mx), e2 = expf(s2 - mx);
            float sm = e0 + e1 + e2;
            #pragma unroll
            for (int off = 32; off; off >>= 1) sm += __shfl_xor(sm, off);
            float inv = 1.0f / sm;
            wsm[wv][k0] = e0 * inv;
            wsm[wv][k1] = e1 * inv;
            wsm[wv][k2] = e2 * inv;
        }
        __syncthreads();
        if (act) {
            float4 acc = make_float4(0.f, 0.f, 0.f, 0.f);
            const float* vbase = base + 1024 + (f4i << 2);
            for (int k = kg; k < NTOK; k += 4) {
                float wgt = wsm[wv][k];
                float4 v = *(const float4*)(vbase + (size_t)k * 1536);
                acc.x += wgt * v.x; acc.y += wgt * v.y; acc.z += wgt * v.z; acc.w += wgt * v.w;
            }
            #pragma unroll
            for (int off = 16; off < 64; off <<= 1) {
                acc.x += __shfl_xor(acc.x, off);
                acc.y += __shfl_xor(acc.y, off);
                acc.z += __shfl_xor(acc.z, off);
                acc.w += __shfl_xor(acc.w, off);
            }
            if (lane < 16)
                *(ushort4*)(outb + (size_t)(b * NTOK + q) * 512 + hh * 64 + (lane << 2)) =
                    make_ushort4(f2h(acc.x), f2h(acc.y), f2h(acc.z), f2h(acc.w));
        }
        __syncthreads();
    }
}

// ---------------- x = LayerNorm(x + y) * g + b ; writes f32 x and f16 xb ----
__global__ __launch_bounds__(256) void lnres_kernel(float* __restrict__ x, ushort* __restrict__ xb,
                                                    const float* __restrict__ y,
                                                    const float* __restrict__ g, const float* __restrict__ bb) {
    const int row = blockIdx.x * 4 + (threadIdx.x >> 6);
    const int l = threadIdx.x & 63;
    float* xr = x + (size_t)row * 512;
    ushort* xbr = xb + (size_t)row * 512;
    const float* yr = y + (size_t)row * 512;
    float4 v0 = *(const float4*)(xr + (l << 2));
    float4 v1 = *(const float4*)(xr + 256 + (l << 2));
    const float4 u0 = *(const float4*)(yr + (l << 2));
    const float4 u1 = *(const float4*)(yr + 256 + (l << 2));
    v0.x += u0.x; v0.y += u0.y; v0.z += u0.z; v0.w += u0.w;
    v1.x += u1.x; v1.y += u1.y; v1.z += u1.z; v1.w += u1.w;
    float s = v0.x + v0.y + v0.z + v0.w + v1.x + v1.y + v1.z + v1.w;
    #pragma unroll
    for (int off = 32; off; off >>= 1) s += __shfl_xor(s, off);
    const float m = s * (1.0f / 512.0f);
    float d0 = v0.x - m, d1 = v0.y - m, d2 = v0.z - m, d3 = v0.w - m;
    float d4 = v1.x - m, d5 = v1.y - m, d6 = v1.z - m, d7 = v1.w - m;
    float q = d0*d0 + d1*d1 + d2*d2 + d3*d3 + d4*d4 + d5*d5 + d6*d6 + d7*d7;
    #pragma unroll
    for (int off = 32; off; off >>= 1) q += __shfl_xor(q, off);
    const float r = rsqrtf(q * (1.0f / 512.0f) + 1e-5f);
    const float4 g0 = *(const float4*)(g + (l << 2));
    const float4 g1 = *(const float4*)(g + 256 + (l << 2));
    const float4 b0 = *(const float4*)(bb + (l << 2));
    const float4 b1 = *(const float4*)(bb + 256 + (l << 2));
    float4 o0, o1;
    o0.x = d0 * r * g0.x + b0.x; o0.y = d1 * r * g0.y + b0.y;
    o0.z = d2 * r * g0.z + b0.z; o0.w = d3 * r * g0.w + b0.w;
    o1.x = d4 * r * g1.x + b1.x; o1.y = d5 * r * g1.y + b1.y;
    o1.z = d6 * r * g1.z + b1.z; o1.w = d7 * r * g1.w + b1.w;
    *(float4*)(xr + (l << 2)) = o0;
    *(float4*)(xr + 256 + (l << 2)) = o1;
    *(ushort4*)(xbr + (l << 2)) = make_ushort4(f2h(o0.x), f2h(o0.y), f2h(o0.z), f2h(o0.w));
    *(ushort4*)(xbr + 256 + (l << 2)) = make_ushort4(f2h(o1.x), f2h(o1.y), f2h(o1.z), f2h(o1.w));
}

// ---------------- head MLP: shift = relu(x@w1+b1)@w2+b2 ; wave per row -------
__global__ __launch_bounds__(256) void head_kernel(const float* __restrict__ x, const float* __restrict__ w1,
                                                   const float* __restrict__ b1, const float* __restrict__ w2,
                                                   const float* __restrict__ b2, float* __restrict__ shift) {
    const int row = blockIdx.x * 4 + (threadIdx.x >> 6);
    const int j = threadIdx.x & 63;
    const float* xr = x + (size_t)row * 512;
    float acc = 0.f;
    #pragma unroll 4
    for (int d = 0; d < 512; d += 4) {
        const float4 xv = *(const float4*)(xr + d);
        acc += xv.x * w1[(d + 0) * 64 + j];
        acc += xv.y * w1[(d + 1) * 64 + j];
        acc += xv.z * w1[(d + 2) * 64 + j];
        acc += xv.w * w1[(d + 3) * 64 + j];
    }
    float h = fmaxf(acc + b1[j], 0.f) * w2[j];
    #pragma unroll
    for (int off = 32; off; off >>= 1) h += __shfl_xor(h, off);
    if (j == 0) shift[row] = h + b2[0];
}

// ---------------- bilinear warp ----------------------------------------------
__global__ void warp_kernel(const float* __restrict__ x0, const float* __restrict__ shift,
                            const int* __restrict__ pms, float* __restrict__ warped) {
    int idx = blockIdx.x * 256 + threadIdx.x;
    if (idx >= M_ROWS * 512) return;
    int c = idx & 511;
    int m = idx >> 9;
    int t = m % NTOK;
    int b = m / NTOK;
    float max_shift = (float)pms[0];
    float sh = shift[m];
    float flow = sh * max_shift / 256.0f;
    float gx = 2.0f * ((float)c / 511.0f - 0.5f) + flow;
    float ix = ((gx + 1.0f) * 512.0f - 1.0f) * 0.5f;
    ix = fminf(fmaxf(ix, 0.0f), 511.0f);
    float gy = 2.0f * ((float)t / 180.0f - 0.5f);
    float iy = ((gy + 1.0f) * 181.0f - 1.0f) * 0.5f;
    iy = fminf(fmaxf(iy, 0.0f), 180.0f);
    float ix0f = floorf(ix), iy0f = floorf(iy);
    float wx = ix - ix0f, wy = iy - iy0f;
    int ix0 = min(max((int)ix0f, 0), 511);
    int ix1 = min(ix0 + 1, 511);
    int iy0 = min(max((int)iy0f, 0), 180);
    int iy1 = min(iy0 + 1, 180);
    const float* xb = x0 + (size_t)b * NTOK * 512;
    float v00 = xb[iy0 * 512 + ix0], v01 = xb[iy0 * 512 + ix1];
    float v10 = xb[iy1 * 512 + ix0], v11 = xb[iy1 * 512 + ix1];
    warped[idx] = (1.f - wy) * ((1.f - wx) * v00 + wx * v01) + wy * ((1.f - wx) * v10 + wx * v11);
}

extern "C" void kernel_launch(void* const* d_in, const int* in_sizes, int n_in,
                              void* d_out, int out_size, void* d_ws, size_t ws_size,
                              hipStream_t stream) {
    const float* x0   = (const float*)d_in[0];
    const int*   pms  = (const int*)d_in[1];
    const float* pos  = (const float*)d_in[2];
    const float* qkvw = (const float*)d_in[3];
    const float* qkvb = (const float*)d_in[4];
    const float* outw = (const float*)d_in[5];
    const float* outbp= (const float*)d_in[6];
    const float* relp = (const float*)d_in[7];
    const float* rpew = (const float*)d_in[8];
    const float* ln1g = (const float*)d_in[9];
    const float* ln1b = (const float*)d_in[10];
    const float* fw1  = (const float*)d_in[11];
    const float* fb1  = (const float*)d_in[12];
    const float* fw2  = (const float*)d_in[13];
    const float* fb2  = (const float*)d_in[14];
    const float* ln2g = (const float*)d_in[15];
    const float* ln2b = (const float*)d_in[16];
    const float* mw1  = (const float*)d_in[17];
    const float* mb1  = (const float*)d_in[18];
    const float* mw2  = (const float*)d_in[19];
    const float* mb2  = (const float*)d_in[20];

    float* out = (float*)d_out;

    char* ws = (char*)d_ws;
    float*  x     = (float*)ws;                               // 11,862,016 B
    ushort* xb    = (ushort*)(ws + 11862016);                 //  5,931,008 B
    char*   qr    = ws + 11862016 + 5931008;                  // 35,586,048 B (qkv | ybuf+hbuf)
    float*  qkv   = (float*)qr;
    float*  ybuf  = (float*)qr;                               // aliases qkv[0:11.8MB]
    ushort* hbuf  = (ushort*)(qr + 11862016);                 // aliases qkv[11.8:35.6MB]
    ushort* attnb = (ushort*)(qr + 35586048);                 //  5,931,008 B
    float*  rbias = (float*)(qr + 35586048 + 5931008);        //      2,048 B
    ushort* wts   = (ushort*)(qr + 35586048 + 5931008 + 2048);
    ushort* qkv_wt = wts;                                     // 6*1536*512
    ushort* out_wt = qkv_wt + 6 * 1536 * 512;                 // 6*512*512
    ushort* f1_wt  = out_wt + 6 * 512 * 512;                  // 6*2048*512
    ushort* f2_wt  = f1_wt  + 6 * 512 * 2048;                 // 6*512*2048

    // preprocess weights: f32 [K][N] -> f16 [N][K]
    wt_kernel<<<dim3(8, 24, 6), 256, 0, stream>>>(qkvw, qkv_wt, 512, 1536);
    wt_kernel<<<dim3(8,  8, 6), 256, 0, stream>>>(outw, out_wt, 512, 512);
    wt_kernel<<<dim3(8, 32, 6), 256, 0, stream>>>(fw1,  f1_wt,  512, 2048);
    wt_kernel<<<dim3(32, 8, 6), 256, 0, stream>>>(fw2,  f2_wt,  2048, 512);

    add_pos_kernel<<<(M_ROWS * 128 + 255) / 256, 256, 0, stream>>>(x0, pos, x, xb);

    for (int i = 0; i < NLAYER; ++i) {
        rbias_kernel<<<6, 64, 0, stream>>>(relp + (size_t)i * (2 * NTOK - 1) * 64, rpew + i * 64, rbias);
        mfma_gemm<128, 0><<<dim3(46, 12), 256, 0, stream>>>(xb, qkv_wt + (size_t)i * 1536 * 512,
                                                            qkvb + i * 1536, qkv, M_ROWS, 512, 1536);
        attn_kernel<<<2048, 256, 0, stream>>>(qkv, rbias, attnb);
        mfma_gemm<64, 0><<<dim3(91, 4), 256, 0, stream>>>(attnb, out_wt + (size_t)i * 512 * 512,
                                                          outbp + i * 512, ybuf, M_ROWS, 512, 512);
        lnres_kernel<<<1448, 256, 0, stream>>>(x, xb, ybuf, ln1g + i * 512, ln1b + i * 512);
        mfma_gemm<128, 1><<<dim3(46, 16), 256, 0, stream>>>(xb, f1_wt + (size_t)i * 2048 * 512,
                                                            fb1 + i * 2048, hbuf, M_ROWS, 512, 2048);
        mfma_gemm<64, 0><<<dim3(91, 4), 256, 0, stream>>>(hbuf, f2_wt + (size_t)i * 512 * 2048,
                                                          fb2 + i * 512, ybuf, M_ROWS, 2048, 512);
        lnres_kernel<<<1448, 256, 0, stream>>>(x, xb, ybuf, ln2g + i * 512, ln2b + i * 512);
    }

    head_kernel<<<1448, 256, 0, stream>>>(x, mw1, mb1, mw2, mb2, out);
    warp_kernel<<<(M_ROWS * 512 + 255) / 256, 256, 0, stream>>>(x0, out, pms, out + M_ROWS);
}

// Round 4
// 905.587 us; speedup vs baseline: 6.5173x; 2.8586x over previous
//
#include <hip/hip_runtime.h>
#include <hip/hip_bf16.h>
#include <math.h>

#define M_ROWS 5792   // B*N
#define NTOK 181
#define NLAYER 6

typedef __attribute__((ext_vector_type(8))) _Float16 f16x8;
typedef __attribute__((ext_vector_type(4))) float f32x4;
typedef __attribute__((ext_vector_type(16))) float f32x16;

__device__ __forceinline__ ushort f2h(float f) {
    union { _Float16 h; ushort u; } v;
    v.h = (_Float16)f;            // v_cvt_f16_f32, round-to-nearest-even
    return v.u;
}
__device__ __forceinline__ float gelu_f(float v) {
    return 0.5f * v * (1.0f + erff(v * 0.70710678118654752f));
}
__device__ __forceinline__ void async16(const void* g, void* l) {
    __builtin_amdgcn_global_load_lds((const __attribute__((address_space(1))) void*)g,
                                     (__attribute__((address_space(3))) void*)l, 16, 0, 0);
}

// ---------------- weight transpose + f16 convert: W[K][N] f32 -> Wt[N][K] f16 ---
__global__ __launch_bounds__(256) void wt_kernel(const float* __restrict__ W,
                                                 ushort* __restrict__ Wt, int K, int N) {
    __shared__ float t[64][65];
    const size_t ls = (size_t)blockIdx.z * K * N;
    const float* Wl = W + ls;
    ushort* Wtl = Wt + ls;
    const int k0 = blockIdx.x * 64, n0 = blockIdx.y * 64;
    const int tr = threadIdx.x >> 6, tc = threadIdx.x & 63;
    #pragma unroll
    for (int i = 0; i < 16; ++i) {
        const int r = i * 4 + tr;
        t[r][tc] = Wl[(size_t)(k0 + r) * N + n0 + tc];
    }
    __syncthreads();
    #pragma unroll
    for (int i = 0; i < 16; ++i) {
        const int r = i * 4 + tr;
        Wtl[(size_t)(n0 + r) * K + k0 + tc] = f2h(t[tc][r]);
    }
}

// ---------------- x = x0 + pos_embed (f32 + f16 shadow) ----------------
__global__ void add_pos_kernel(const float* __restrict__ x0, const float* __restrict__ pos,
                               float* __restrict__ x, ushort* __restrict__ xb) {
    int idx = blockIdx.x * 256 + threadIdx.x;          // float4 index
    const int total = M_ROWS * 128;
    if (idx >= total) return;
    int col = idx & 127;
    int m   = idx >> 7;
    int t   = m % NTOK;
    float4 a = ((const float4*)x0)[idx];
    float4 p = ((const float4*)pos)[t * 128 + col];
    a.x += p.x; a.y += p.y; a.z += p.z; a.w += p.w;
    ((float4*)x)[idx] = a;
    ((ushort4*)xb)[idx] = make_ushort4(f2h(a.x), f2h(a.y), f2h(a.z), f2h(a.w));
}

// ---------------- f16 MFMA GEMM: C = A(MxK,f16) @ Bt(NxK,f16)^T + bias --------
// BM x 128 tile, BK=32, 4 waves (2x2). EPI: 0 = f32 out, 1 = gelu->f16, 2 = f16
template<int BM, int EPI>
__global__ __launch_bounds__(256) void mfma_gemm(const ushort* __restrict__ A,
                                                 const ushort* __restrict__ Bt,
                                                 const float* __restrict__ bias,
                                                 void* __restrict__ Cv,
                                                 int M, int K, int N) {
    constexpr int MREP = BM / 32;
    __shared__ __align__(16) ushort sA[2][BM * 32];
    __shared__ __align__(16) ushort sB[2][128 * 32];
    const int tid = threadIdx.x;
    const int lane = tid & 63;
    const int w = tid >> 6;
    const int wr = w >> 1, wc = w & 1;
    const int row0 = blockIdx.x * BM, col0 = blockIdx.y * 128;
    const int wbase = tid & ~63;

    f32x4 acc[MREP][4];
    const f32x4 zero = {0.f, 0.f, 0.f, 0.f};
    #pragma unroll
    for (int m = 0; m < MREP; ++m)
        #pragma unroll
        for (int n = 0; n < 4; ++n) acc[m][n] = zero;

    auto stage = [&](int buf, int kt) {
        const int k0 = kt << 5;
        #pragma unroll
        for (int i = 0; i < BM / 64; ++i) {
            const int s = i * 256 + tid;           // 16B slot
            const int row = s >> 2;
            const int kbl = (s & 3) ^ ((row >> 1) & 3);   // pre-swizzled source
            int gr = row0 + row; if (gr > M - 1) gr = M - 1;
            async16(A + (size_t)gr * K + k0 + (kbl << 3),
                    &sA[buf][(i * 256 + wbase) * 8]);
        }
        #pragma unroll
        for (int i = 0; i < 2; ++i) {
            const int s = i * 256 + tid;
            const int nr = s >> 2;
            const int kbl = (s & 3) ^ ((nr >> 1) & 3);
            async16(Bt + (size_t)(col0 + nr) * K + k0 + (kbl << 3),
                    &sB[buf][(i * 256 + wbase) * 8]);
        }
    };

    stage(0, 0);
    const int NIT = K >> 5;
    const int l15 = lane & 15, kb = lane >> 4;
    for (int it = 0; it < NIT; ++it) {
        __syncthreads();
        if (it + 1 < NIT) stage((it + 1) & 1, it + 1);
        const int buf = it & 1;
        f16x8 af[MREP], bfr[4];
        #pragma unroll
        for (int m = 0; m < MREP; ++m) {
            const int r = wr * (BM / 2) + m * 16 + l15;
            af[m] = *(const f16x8*)&sA[buf][r * 32 + ((kb ^ ((r >> 1) & 3)) << 3)];
        }
        #pragma unroll
        for (int n = 0; n < 4; ++n) {
            const int r = wc * 64 + n * 16 + l15;
            bfr[n] = *(const f16x8*)&sB[buf][r * 32 + ((kb ^ ((r >> 1) & 3)) << 3)];
        }
        #pragma unroll
        for (int m = 0; m < MREP; ++m)
            #pragma unroll
            for (int n = 0; n < 4; ++n)
                acc[m][n] = __builtin_amdgcn_mfma_f32_16x16x32_f16(af[m], bfr[n], acc[m][n], 0, 0, 0);
    }

    const int crow = row0 + wr * (BM / 2) + (lane >> 4) * 4;
    const int ccol = col0 + wc * 64 + l15;
    #pragma unroll
    for (int m = 0; m < MREP; ++m)
        #pragma unroll
        for (int n = 0; n < 4; ++n) {
            const int gc = ccol + n * 16;
            const float bv = bias[gc];
            #pragma unroll
            for (int r = 0; r < 4; ++r) {
                const int gr = crow + m * 16 + r;
                if (gr < M) {
                    float v = acc[m][n][r] + bv;
                    if (EPI == 1)      ((ushort*)Cv)[(size_t)gr * N + gc] = f2h(gelu_f(v));
                    else if (EPI == 2) ((ushort*)Cv)[(size_t)gr * N + gc] = f2h(v);
                    else               ((float*)Cv)[(size_t)gr * N + gc] = v;
                }
            }
        }
}

// ---------------- relative-position bias r[j] = dot(rel_pos[j], rpe_w) --------
__global__ void rbias_kernel(const float* __restrict__ rel_pos, const float* __restrict__ rpe_w,
                             float* __restrict__ r) {
    int j = blockIdx.x * 64 + threadIdx.x;
    if (j >= 2 * NTOK - 1) return;
    const float* rp = rel_pos + (size_t)j * 64;
    float s = 0.f;
    #pragma unroll
    for (int d = 0; d < 64; d += 4) {
        float4 a = *(const float4*)(rp + d);
        float4 b = *(const float4*)(rpe_w + d);
        s += a.x*b.x + a.y*b.y + a.z*b.z + a.w*b.w;
    }
    r[j] = s;
}

// ---------------- MFMA attention: one block per (b,h), 6 waves, 32 q-rows/wave ---
// T padded to 192 (6 k-tiles of 32). S^T = mfma(K,Q) per tile; softmax in-register
// on the verified C/D layout; P round-trips through LDS so the (unverified) A/B
// k-fragment mapping cancels between the P and V operands of the PV MFMA.
__global__ __launch_bounds__(384, 2) void attn_mfma(const ushort* __restrict__ qkv,
                                                    const float* __restrict__ rb,
                                                    ushort* __restrict__ outb) {
    __shared__ __align__(16) ushort sm[36864];  // Qs[0:12288] Ks[12288:24576]; Ps aliases all
    __shared__ __align__(16) ushort vt[12288];  // V transposed [64][192], slot-swizzled
    __shared__ float rs[416];                   // bias, offset +32, zero-padded
    const int b  = blockIdx.x >> 3;
    const int h  = blockIdx.x & 7;
    const int tid = threadIdx.x, lane = tid & 63, w = tid >> 6;
    const int l31 = lane & 31, hi = lane >> 5;
    const ushort* base = qkv + (size_t)(b * NTOK) * 1536 + h * 64;

    // bias table
    for (int i = tid; i < 416; i += 384) {
        int j = i - 32;
        rs[i] = (j >= 0 && j < 2 * NTOK - 1) ? rb[j] : 0.f;
    }
    // stage Q,K: global_load_lds, inverse-swizzled source, linear dest
    #pragma unroll
    for (int i = 0; i < 4; ++i) {
        const int c = w * 256 + i * 64 + lane;      // 16B chunk id, 0..1535
        const int q = c >> 3;
        const int qq = q < NTOK ? q : NTOK - 1;
        const int dc = (c & 7) ^ (q & 7);           // logical d-chunk for this slot
        async16(base + (size_t)qq * 1536 + dc * 8,        &sm[(w * 256 + i * 64) * 8]);
        async16(base + (size_t)qq * 1536 + 512 + dc * 8,  &sm[12288 + (w * 256 + i * 64) * 8]);
    }
    // stage V transposed: vt[d][k], phys slot = (k>>3) ^ ((d^(d>>3))&7)
    #pragma unroll
    for (int i = 0; i < 4; ++i) {
        const int c = tid + i * 384;
        const int k = c >> 3, dc = c & 7;
        const int kk = k < NTOK ? k : NTOK - 1;
        const uint4 v = *(const uint4*)(base + (size_t)kk * 1536 + 1024 + dc * 8);
        const uint vv[4] = {v.x, v.y, v.z, v.w};
        #pragma unroll
        for (int j = 0; j < 4; ++j) {
            const int d0 = dc * 8 + j * 2, d1 = d0 + 1;
            vt[d0 * 192 + ((((k >> 3) ^ ((d0 ^ (d0 >> 3)) & 7)) << 3) + (k & 7))] = (ushort)(vv[j] & 0xffffu);
            vt[d1 * 192 + ((((k >> 3) ^ ((d1 ^ (d1 >> 3)) & 7)) << 3) + (k & 7))] = (ushort)(vv[j] >> 16);
        }
    }
    __syncthreads();

    const int q = 32 * w + l31;                      // this lane's q-column (S^T)
    // Q fragments (reused across k-tiles)
    f16x8 qf[4];
    #pragma unroll
    for (int ds = 0; ds < 4; ++ds)
        qf[ds] = *(const f16x8*)&sm[q * 64 + (((2 * ds + hi) ^ (q & 7)) << 3)];

    // S^T[k][q] accumulation
    f32x16 S[6];
    #pragma unroll
    for (int kt = 0; kt < 6; ++kt)
        #pragma unroll
        for (int r = 0; r < 16; ++r) S[kt][r] = 0.f;
    #pragma unroll
    for (int kt = 0; kt < 6; ++kt) {
        const int krow = kt * 32 + l31;
        #pragma unroll
        for (int ds = 0; ds < 4; ++ds) {
            f16x8 kf = *(const f16x8*)&sm[12288 + krow * 64 + (((2 * ds + hi) ^ (krow & 7)) << 3)];
            S[kt] = __builtin_amdgcn_mfma_f32_32x32x16_f16(kf, qf[ds], S[kt], 0, 0, 0);
        }
    }

    // bias + mask + softmax (C/D layout: row k = (r&3)+8*(r>>2)+4*hi, col q = l31)
    float mx = -1e30f;
    #pragma unroll
    for (int kt = 0; kt < 6; ++kt)
        #pragma unroll
        for (int r = 0; r < 16; ++r) {
            const int k = kt * 32 + (r & 3) + 8 * (r >> 2) + 4 * hi;
            float s = (k < NTOK) ? S[kt][r] * 0.125f + rs[k - q + 212] : -1e30f;
            S[kt][r] = s;
            mx = fmaxf(mx, s);
        }
    mx = fmaxf(mx, __shfl_xor(mx, 32));
    float sum = 0.f;
    #pragma unroll
    for (int kt = 0; kt < 6; ++kt)
        #pragma unroll
        for (int r = 0; r < 16; ++r) {
            float e = __expf(S[kt][r] - mx);
            S[kt][r] = e;
            sum += e;
        }
    sum += __shfl_xor(sum, 32);
    const float inv = 1.0f / sum;

    __syncthreads();    // all QK^T LDS reads done; safe to overwrite Qs/Ks with P

    // write normalized P[q][k] f16 into warp-private LDS (row = q = l31)
    const int sq = (l31 ^ (l31 >> 3)) & 7;
    #pragma unroll
    for (int kt = 0; kt < 6; ++kt)
        #pragma unroll
        for (int r = 0; r < 16; r += 2) {
            const int k = kt * 32 + (r & 3) + 8 * (r >> 2) + 4 * hi;   // even
            const uint pk = (uint)f2h(S[kt][r] * inv) | ((uint)f2h(S[kt][r + 1] * inv) << 16);
            *(uint*)&sm[w * 6144 + l31 * 192 + ((((k >> 3) ^ sq) << 3) + (k & 7))] = pk;
        }
    __syncthreads();

    // PV: O[q][d] = sum_k P[q][k] V[k][d]; both operands from LDS (k-mapping cancels)
    f32x16 O[2];
    #pragma unroll
    for (int nt = 0; nt < 2; ++nt)
        #pragma unroll
        for (int r = 0; r < 16; ++r) O[nt][r] = 0.f;
    #pragma unroll
    for (int kt2 = 0; kt2 < 12; ++kt2) {
        f16x8 pa = *(const f16x8*)&sm[w * 6144 + l31 * 192 + ((((2 * kt2 + hi) ^ sq) << 3))];
        #pragma unroll
        for (int nt = 0; nt < 2; ++nt) {
            const int d = nt * 32 + l31;
            f16x8 vf = *(const f16x8*)&vt[d * 192 + (((2 * kt2 + hi) ^ ((d ^ (d >> 3)) & 7)) << 3)];
            O[nt] = __builtin_amdgcn_mfma_f32_32x32x16_f16(pa, vf, O[nt], 0, 0, 0);
        }
    }

    // store (C/D layout: row = q-within-warp, col = d)
    #pragma unroll
    for (int nt = 0; nt < 2; ++nt)
        #pragma unroll
        for (int r = 0; r < 16; ++r) {
            const int qr = 32 * w + (r & 3) + 8 * (r >> 2) + 4 * hi;
            if (qr < NTOK)
                outb[(size_t)(b * NTOK + qr) * 512 + h * 64 + nt * 32 + l31] = f2h(O[nt][r]);
        }
}

// ---------------- x = LayerNorm(x + y) * g + b ; writes f32 x and f16 xb ----
__global__ __launch_bounds__(256) void lnres_kernel(float* __restrict__ x, ushort* __restrict__ xb,
                                                    const float* __restrict__ y,
                                                    const float* __restrict__ g, const float* __restrict__ bb) {
    const int row = blockIdx.x * 4 + (threadIdx.x >> 6);
    const int l = threadIdx.x & 63;
    float* xr = x + (size_t)row * 512;
    ushort* xbr = xb + (size_t)row * 512;
    const float* yr = y + (size_t)row * 512;
    float4 v0 = *(const float4*)(xr + (l << 2));
    float4 v1 = *(const float4*)(xr + 256 + (l << 2));
    const float4 u0 = *(const float4*)(yr + (l << 2));
    const float4 u1 = *(const float4*)(yr + 256 + (l << 2));
    v0.x += u0.x; v0.y += u0.y; v0.z += u0.z; v0.w += u0.w;
    v1.x += u1.x; v1.y += u1.y; v1.z += u1.z; v1.w += u1.w;
    float s = v0.x + v0.y + v0.z + v0.w + v1.x + v1.y + v1.z + v1.w;
    #pragma unroll
    for (int off = 32; off; off >>= 1) s += __shfl_xor(s, off);
    const float m = s * (1.0f / 512.0f);
    float d0 = v0.x - m, d1 = v0.y - m, d2 = v0.z - m, d3 = v0.w - m;
    float d4 = v1.x - m, d5 = v1.y - m, d6 = v1.z - m, d7 = v1.w - m;
    float q = d0*d0 + d1*d1 + d2*d2 + d3*d3 + d4*d4 + d5*d5 + d6*d6 + d7*d7;
    #pragma unroll
    for (int off = 32; off; off >>= 1) q += __shfl_xor(q, off);
    const float r = rsqrtf(q * (1.0f / 512.0f) + 1e-5f);
    const float4 g0 = *(const float4*)(g + (l << 2));
    const float4 g1 = *(const float4*)(g + 256 + (l << 2));
    const float4 b0 = *(const float4*)(bb + (l << 2));
    const float4 b1 = *(const float4*)(bb + 256 + (l << 2));
    float4 o0, o1;
    o0.x = d0 * r * g0.x + b0.x; o0.y = d1 * r * g0.y + b0.y;
    o0.z = d2 * r * g0.z + b0.z; o0.w = d3 * r * g0.w + b0.w;
    o1.x = d4 * r * g1.x + b1.x; o1.y = d5 * r * g1.y + b1.y;
    o1.z = d6 * r * g1.z + b1.z; o1.w = d7 * r * g1.w + b1.w;
    *(float4*)(xr + (l << 2)) = o0;
    *(float4*)(xr + 256 + (l << 2)) = o1;
    *(ushort4*)(xbr + (l << 2)) = make_ushort4(f2h(o0.x), f2h(o0.y), f2h(o0.z), f2h(o0.w));
    *(ushort4*)(xbr + 256 + (l << 2)) = make_ushort4(f2h(o1.x), f2h(o1.y), f2h(o1.z), f2h(o1.w));
}

// ---------------- head MLP: shift = relu(x@w1+b1)@w2+b2 ; wave per row -------
__global__ __launch_bounds__(256) void head_kernel(const float* __restrict__ x, const float* __restrict__ w1,
                                                   const float* __restrict__ b1, const float* __restrict__ w2,
                                                   const float* __restrict__ b2, float* __restrict__ shift) {
    const int row = blockIdx.x * 4 + (threadIdx.x >> 6);
    const int j = threadIdx.x & 63;
    const float* xr = x + (size_t)row * 512;
    float acc = 0.f;
    #pragma unroll 4
    for (int d = 0; d < 512; d += 4) {
        const float4 xv = *(const float4*)(xr + d);
        acc += xv.x * w1[(d + 0) * 64 + j];
        acc += xv.y * w1[(d + 1) * 64 + j];
        acc += xv.z * w1[(d + 2) * 64 + j];
        acc += xv.w * w1[(d + 3) * 64 + j];
    }
    float h = fmaxf(acc + b1[j], 0.f) * w2[j];
    #pragma unroll
    for (int off = 32; off; off >>= 1) h += __shfl_xor(h, off);
    if (j == 0) shift[row] = h + b2[0];
}

// ---------------- bilinear warp ----------------------------------------------
__global__ void warp_kernel(const float* __restrict__ x0, const float* __restrict__ shift,
                            const int* __restrict__ pms, float* __restrict__ warped) {
    int idx = blockIdx.x * 256 + threadIdx.x;
    if (idx >= M_ROWS * 512) return;
    int c = idx & 511;
    int m = idx >> 9;
    int t = m % NTOK;
    int b = m / NTOK;
    float max_shift = (float)pms[0];
    float sh = shift[m];
    float flow = sh * max_shift / 256.0f;
    float gx = 2.0f * ((float)c / 511.0f - 0.5f) + flow;
    float ix = ((gx + 1.0f) * 512.0f - 1.0f) * 0.5f;
    ix = fminf(fmaxf(ix, 0.0f), 511.0f);
    float gy = 2.0f * ((float)t / 180.0f - 0.5f);
    float iy = ((gy + 1.0f) * 181.0f - 1.0f) * 0.5f;
    iy = fminf(fmaxf(iy, 0.0f), 180.0f);
    float ix0f = floorf(ix), iy0f = floorf(iy);
    float wx = ix - ix0f, wy = iy - iy0f;
    int ix0 = min(max((int)ix0f, 0), 511);
    int ix1 = min(ix0 + 1, 511);
    int iy0 = min(max((int)iy0f, 0), 180);
    int iy1 = min(iy0 + 1, 180);
    const float* xb = x0 + (size_t)b * NTOK * 512;
    float v00 = xb[iy0 * 512 + ix0], v01 = xb[iy0 * 512 + ix1];
    float v10 = xb[iy1 * 512 + ix0], v11 = xb[iy1 * 512 + ix1];
    warped[idx] = (1.f - wy) * ((1.f - wx) * v00 + wx * v01) + wy * ((1.f - wx) * v10 + wx * v11);
}

extern "C" void kernel_launch(void* const* d_in, const int* in_sizes, int n_in,
                              void* d_out, int out_size, void* d_ws, size_t ws_size,
                              hipStream_t stream) {
    const float* x0   = (const float*)d_in[0];
    const int*   pms  = (const int*)d_in[1];
    const float* pos  = (const float*)d_in[2];
    const float* qkvw = (const float*)d_in[3];
    const float* qkvb = (const float*)d_in[4];
    const float* outw = (const float*)d_in[5];
    const float* outbp= (const float*)d_in[6];
    const float* relp = (const float*)d_in[7];
    const float* rpew = (const float*)d_in[8];
    const float* ln1g = (const float*)d_in[9];
    const float* ln1b = (const float*)d_in[10];
    const float* fw1  = (const float*)d_in[11];
    const float* fb1  = (const float*)d_in[12];
    const float* fw2  = (const float*)d_in[13];
    const float* fb2  = (const float*)d_in[14];
    const float* ln2g = (const float*)d_in[15];
    const float* ln2b = (const float*)d_in[16];
    const float* mw1  = (const float*)d_in[17];
    const float* mb1  = (const float*)d_in[18];
    const float* mw2  = (const float*)d_in[19];
    const float* mb2  = (const float*)d_in[20];

    float* out = (float*)d_out;

    char* ws = (char*)d_ws;
    float*  x     = (float*)ws;                               // 11,862,016 B
    ushort* xb    = (ushort*)(ws + 11862016);                 //  5,931,008 B
    char*   qr    = ws + 11862016 + 5931008;                  // 35,586,048 B region
    ushort* qkv   = (ushort*)qr;                              // f16 qkv (17.8MB used)
    float*  ybuf  = (float*)qr;                               // aliases qkv (dead by then)
    ushort* hbuf  = (ushort*)(qr + 11862016);                 // aliases qkv tail
    ushort* attnb = (ushort*)(qr + 35586048);                 //  5,931,008 B
    float*  rbias = (float*)(qr + 35586048 + 5931008);        //      2,048 B
    ushort* wts   = (ushort*)(qr + 35586048 + 5931008 + 2048);
    ushort* qkv_wt = wts;                                     // 6*1536*512
    ushort* out_wt = qkv_wt + 6 * 1536 * 512;                 // 6*512*512
    ushort* f1_wt  = out_wt + 6 * 512 * 512;                  // 6*2048*512
    ushort* f2_wt  = f1_wt  + 6 * 512 * 2048;                 // 6*512*2048

    // preprocess weights: f32 [K][N] -> f16 [N][K]
    wt_kernel<<<dim3(8, 24, 6), 256, 0, stream>>>(qkvw, qkv_wt, 512, 1536);
    wt_kernel<<<dim3(8,  8, 6), 256, 0, stream>>>(outw, out_wt, 512, 512);
    wt_kernel<<<dim3(8, 32, 6), 256, 0, stream>>>(fw1,  f1_wt,  512, 2048);
    wt_kernel<<<dim3(32, 8, 6), 256, 0, stream>>>(fw2,  f2_wt,  2048, 512);

    add_pos_kernel<<<(M_ROWS * 128 + 255) / 256, 256, 0, stream>>>(x0, pos, x, xb);

    for (int i = 0; i < NLAYER; ++i) {
        rbias_kernel<<<6, 64, 0, stream>>>(relp + (size_t)i * (2 * NTOK - 1) * 64, rpew + i * 64, rbias);
        mfma_gemm<128, 2><<<dim3(46, 12), 256, 0, stream>>>(xb, qkv_wt + (size_t)i * 1536 * 512,
                                                            qkvb + i * 1536, qkv, M_ROWS, 512, 1536);
        attn_mfma<<<256, 384, 0, stream>>>(qkv, rbias, attnb);
        mfma_gemm<64, 0><<<dim3(91, 4), 256, 0, stream>>>(attnb, out_wt + (size_t)i * 512 * 512,
                                                          outbp + i * 512, ybuf, M_ROWS, 512, 512);
        lnres_kernel<<<1448, 256, 0, stream>>>(x, xb, ybuf, ln1g + i * 512, ln1b + i * 512);
        mfma_gemm<128, 1><<<dim3(46, 16), 256, 0, stream>>>(xb, f1_wt + (size_t)i * 2048 * 512,
                                                            fb1 + i * 2048, hbuf, M_ROWS, 512, 2048);
        mfma_gemm<64, 0><<<dim3(91, 4), 256, 0, stream>>>(hbuf, f2_wt + (size_t)i * 512 * 2048,
                                                          fb2 + i * 512, ybuf, M_ROWS, 2048, 512);
        lnres_kernel<<<1448, 256, 0, stream>>>(x, xb, ybuf, ln2g + i * 512, ln2b + i * 512);
    }

    head_kernel<<<1448, 256, 0, stream>>>(x, mw1, mb1, mw2, mb2, out);
    warp_kernel<<<(M_ROWS * 512 + 255) / 256, 256, 0, stream>>>(x0, out, pms, out + M_ROWS);
}